// Round 1
// baseline (668.478 us; speedup 1.0000x reference)
//
#include <hip/hip_runtime.h>
#include <stdint.h>

#define BATCH 8
#define SEQ   4096
#define DIM   1024
#define ROWS  (BATCH * SEQ)   // 32768

typedef __attribute__((ext_vector_type(8))) short short8;
typedef __attribute__((ext_vector_type(4))) float f32x4;

__device__ __forceinline__ unsigned short f2bf(float f) {
  union { float f; unsigned u; } v; v.f = f;
  unsigned r = v.u + 0x7FFFu + ((v.u >> 16) & 1u);  // RNE
  return (unsigned short)(r >> 16);
}
__device__ __forceinline__ float bf2f(unsigned short h) {
  union { unsigned u; float f; } v; v.u = ((unsigned)h) << 16;
  return v.f;
}

__device__ __forceinline__ void gload_lds16(const unsigned short* g, unsigned short* l) {
  __builtin_amdgcn_global_load_lds(
      (const __attribute__((address_space(1))) void*)g,
      (__attribute__((address_space(3))) void*)l,
      16, 0, 0);
}

__device__ __forceinline__ f32x4 mfma16(short8 a, short8 b, f32x4 c) {
  return __builtin_amdgcn_mfma_f32_16x16x32_bf16(a, b, c, 0, 0, 0);
}

// Stage a [128 rows][64 k] bf16 tile into linear LDS (16 KiB) via global_load_lds.
// XOR swizzle (chunk ^ (row&7)) is applied on the GLOBAL source address so the
// linear LDS holds the swizzled layout (rule #21: swizzle both sides or neither).
__device__ __forceinline__ void stage_tile(const unsigned short* __restrict__ src,
                                           int row0, int k0,
                                           unsigned short* lds, int tid) {
#pragma unroll
  for (int i = 0; i < 4; ++i) {
    int s   = tid + 256 * i;      // 16B chunk slot, 1024 chunks total
    int row = s >> 3;             // 8 chunks (128B) per row
    int h   = s & 7;
    int gc  = h ^ (row & 7);      // inverse-swizzled source chunk
    const unsigned short* gp = src + (size_t)(row0 + row) * DIM + (size_t)(k0 + gc * 8);
    unsigned short* lp = lds + (size_t)((tid & ~63) + 256 * i) * 8;  // wave-uniform base
    gload_lds16(gp, lp);
  }
}

// Read one MFMA A/B fragment (contiguous k-permutation, 16B ds_read_b128),
// applying the same XOR swizzle as the staging side.
__device__ __forceinline__ short8 read_frag(const unsigned short* lds, int rowbase,
                                            int r16, int g, int kk) {
  int row  = rowbase + r16;                 // rowbase multiple of 16 -> row&7 == r16&7
  int slot = (g + 4 * kk) ^ (r16 & 7);
  return *(const short8*)(lds + (size_t)row * 64 + (size_t)slot * 8);
}

// ---------------------------------------------------------------------------
__global__ void init_zero_k(float* __restrict__ out, float* __restrict__ norm2) {
  int i = blockIdx.x * 256 + threadIdx.x;
  if (i < ROWS) { out[i] = 0.f; norm2[i] = 0.f; }
}

__global__ void convert_x_k(const float4* __restrict__ x, ushort4* __restrict__ xb, int n4) {
  int i = blockIdx.x * 256 + threadIdx.x;
  if (i < n4) {
    float4 v = x[i];
    ushort4 o;
    o.x = f2bf(v.x); o.y = f2bf(v.y); o.z = f2bf(v.z); o.w = f2bf(v.w);
    xb[i] = o;
  }
}

// Wt[n][k] = W[k][n], bf16.  64x64 tiles via LDS.
__global__ void transpose_w_k(const float* __restrict__ W, unsigned short* __restrict__ Wt) {
  __shared__ unsigned short t[64][65];
  int bx = blockIdx.x & 15;   // col tile of W
  int by = blockIdx.x >> 4;   // row tile of W
  int c  = threadIdx.x & 63;
  int r0 = threadIdx.x >> 6;  // 0..3
#pragma unroll
  for (int i = 0; i < 16; ++i) {
    int r = r0 + i * 4;
    t[r][c] = f2bf(W[(size_t)(by * 64 + r) * DIM + (bx * 64 + c)]);
  }
  __syncthreads();
#pragma unroll
  for (int i = 0; i < 16; ++i) {
    int r = r0 + i * 4;  // row of Wt within tile = original col
    Wt[(size_t)(bx * 64 + r) * DIM + (by * 64 + c)] = t[c][r];
  }
}

// ---------------------------------------------------------------------------
// GEMM1: proj = Xb @ W  (B panel = rows of Wt). Writes bf16 proj + atomic sumsq.
__global__ __launch_bounds__(256) void gemm1_proj(
    const unsigned short* __restrict__ Xb,
    const unsigned short* __restrict__ Wt,
    unsigned short* __restrict__ projb,
    float* __restrict__ norm2) {
  __shared__ __align__(16) unsigned short lA[128 * 64];
  __shared__ __align__(16) unsigned short lB[128 * 64];
  const int tid = threadIdx.x;
  const int lane = tid & 63, wv = tid >> 6;
  const int wr = wv >> 1, wc = wv & 1;
  const int g = lane >> 4, r16 = lane & 15;
  const int mt = blockIdx.x >> 3, nt = blockIdx.x & 7;
  const int arow0 = mt * 128, brow0 = nt * 128;

  f32x4 acc[4][4];
#pragma unroll
  for (int m = 0; m < 4; ++m)
#pragma unroll
    for (int n = 0; n < 4; ++n) acc[m][n] = (f32x4){0.f, 0.f, 0.f, 0.f};

  for (int kt = 0; kt < DIM / 64; ++kt) {
    stage_tile(Xb, arow0, kt * 64, lA, tid);
    stage_tile(Wt, brow0, kt * 64, lB, tid);
    __syncthreads();
#pragma unroll
    for (int kk = 0; kk < 2; ++kk) {
      short8 af[4], bfr[4];
#pragma unroll
      for (int m = 0; m < 4; ++m) af[m] = read_frag(lA, wr * 64 + m * 16, r16, g, kk);
#pragma unroll
      for (int n = 0; n < 4; ++n) bfr[n] = read_frag(lB, wc * 64 + n * 16, r16, g, kk);
#pragma unroll
      for (int m = 0; m < 4; ++m)
#pragma unroll
        for (int n = 0; n < 4; ++n)
          acc[m][n] = mfma16(af[m], bfr[n], acc[m][n]);
    }
    __syncthreads();
  }

  // Epilogue: bf16 store + per-row sum-of-squares (reduce over lane&15 = cols).
#pragma unroll
  for (int m = 0; m < 4; ++m) {
#pragma unroll
    for (int r = 0; r < 4; ++r) {
      int row = arow0 + wr * 64 + m * 16 + 4 * g + r;
      float ss = 0.f;
#pragma unroll
      for (int n = 0; n < 4; ++n) {
        float v = acc[m][n][r];
        projb[(size_t)row * DIM + (brow0 + wc * 64 + n * 16 + r16)] = f2bf(v);
        ss += v * v;
      }
      ss += __shfl_xor(ss, 1);
      ss += __shfl_xor(ss, 2);
      ss += __shfl_xor(ss, 4);
      ss += __shfl_xor(ss, 8);
      if (r16 == 0) atomicAdd(&norm2[row], ss);
    }
  }
}

// In-place: projb[row][*] *= rsqrt(norm2[row])  (8 bf16 per thread)
__global__ void normalize_k(unsigned short* __restrict__ pb, const float* __restrict__ n2) {
  int i = blockIdx.x * 256 + threadIdx.x;  // group of 8 elements
  int row = i >> 7;                        // 1024/8 = 128 groups per row
  float rs = rsqrtf(fmaxf(n2[row], 1e-24f));
  union { short8 v; unsigned short u[8]; } d;
  d.v = *(const short8*)(pb + (size_t)i * 8);
#pragma unroll
  for (int j = 0; j < 8; ++j) d.u[j] = f2bf(bf2f(d.u[j]) * rs);
  *(short8*)(pb + (size_t)i * 8) = d.v;
}

// ---------------------------------------------------------------------------
// GEMM2: per batch, sim-tile = N_s @ N_t^T ; epilogue sigmoid + row-mean atomics.
__global__ __launch_bounds__(256) void gemm2_attn(
    const unsigned short* __restrict__ normed,
    float* __restrict__ out) {
  __shared__ __align__(16) unsigned short lA[128 * 64];
  __shared__ __align__(16) unsigned short lB[128 * 64];
  const int tid = threadIdx.x;
  const int lane = tid & 63, wv = tid >> 6;
  const int wr = wv >> 1, wc = wv & 1;
  const int g = lane >> 4, r16 = lane & 15;
  const int tt = blockIdx.x, st = blockIdx.y, b = blockIdx.z;
  const unsigned short* Nb = normed + (size_t)b * SEQ * DIM;
  const int arow0 = st * 128, brow0 = tt * 128;

  f32x4 acc[4][4];
#pragma unroll
  for (int m = 0; m < 4; ++m)
#pragma unroll
    for (int n = 0; n < 4; ++n) acc[m][n] = (f32x4){0.f, 0.f, 0.f, 0.f};

  for (int kt = 0; kt < DIM / 64; ++kt) {
    stage_tile(Nb, arow0, kt * 64, lA, tid);
    stage_tile(Nb, brow0, kt * 64, lB, tid);
    __syncthreads();
#pragma unroll
    for (int kk = 0; kk < 2; ++kk) {
      short8 af[4], bfr[4];
#pragma unroll
      for (int m = 0; m < 4; ++m) af[m] = read_frag(lA, wr * 64 + m * 16, r16, g, kk);
#pragma unroll
      for (int n = 0; n < 4; ++n) bfr[n] = read_frag(lB, wc * 64 + n * 16, r16, g, kk);
#pragma unroll
      for (int m = 0; m < 4; ++m)
#pragma unroll
        for (int n = 0; n < 4; ++n)
          acc[m][n] = mfma16(af[m], bfr[n], acc[m][n]);
    }
    __syncthreads();
  }

  // Epilogue: sigmoid + sum over the wave's 64 rows, then atomic into out[b][t].
  const float inv = 1.0f / (float)SEQ;
#pragma unroll
  for (int n = 0; n < 4; ++n) {
    float part = 0.f;
#pragma unroll
    for (int m = 0; m < 4; ++m)
#pragma unroll
      for (int r = 0; r < 4; ++r) {
        float x = acc[m][n][r];
        part += 1.0f / (1.0f + __expf(-x));
      }
    part += __shfl_xor(part, 16);
    part += __shfl_xor(part, 32);
    if (g == 0)
      atomicAdd(&out[(size_t)b * SEQ + brow0 + wc * 64 + n * 16 + r16], part * inv);
  }
}

// ---------------------------------------------------------------------------
extern "C" void kernel_launch(void* const* d_in, const int* in_sizes, int n_in,
                              void* d_out, int out_size, void* d_ws, size_t ws_size,
                              hipStream_t stream) {
  const float* x = (const float*)d_in[0];
  const float* W = (const float*)d_in[1];
  float* out = (float*)d_out;

  char* ws = (char*)d_ws;
  unsigned short* Xb    = (unsigned short*)ws;                                   // 64 MiB
  unsigned short* projb = (unsigned short*)(ws + (size_t)ROWS * DIM * 2);        // 64 MiB
  unsigned short* Wt    = (unsigned short*)(ws + (size_t)ROWS * DIM * 4);        // 2 MiB
  float* norm2          = (float*)(ws + (size_t)ROWS * DIM * 4 + (size_t)DIM * DIM * 2);

  hipLaunchKernelGGL(init_zero_k, dim3(ROWS / 256), dim3(256), 0, stream, out, norm2);
  hipLaunchKernelGGL(convert_x_k, dim3((ROWS * DIM / 4) / 256), dim3(256), 0, stream,
                     (const float4*)x, (ushort4*)Xb, ROWS * DIM / 4);
  hipLaunchKernelGGL(transpose_w_k, dim3(256), dim3(256), 0, stream, W, Wt);
  hipLaunchKernelGGL(gemm1_proj, dim3((ROWS / 128) * (DIM / 128)), dim3(256), 0, stream,
                     Xb, Wt, projb, norm2);
  hipLaunchKernelGGL(normalize_k, dim3((ROWS * DIM / 8) / 256), dim3(256), 0, stream,
                     projb, norm2);
  hipLaunchKernelGGL(gemm2_attn, dim3(SEQ / 128, SEQ / 128, BATCH), dim3(256), 0, stream,
                     projb, out);
}

// Round 3
// 515.497 us; speedup vs baseline: 1.2968x; 1.2968x over previous
//
#include <hip/hip_runtime.h>
#include <stdint.h>

#define BATCH 8
#define SEQ   4096
#define DIM   1024
#define ROWS  (BATCH * SEQ)   // 32768
#define NT    (SEQ / 128)     // 32 tiles per dim
#define NPAIR (NT * (NT + 1) / 2)  // 528 triangular tile pairs

typedef __attribute__((ext_vector_type(8))) short short8;
typedef __attribute__((ext_vector_type(4))) float f32x4;

__device__ __forceinline__ unsigned short f2bf(float f) {
  union { float f; unsigned u; } v; v.f = f;
  unsigned r = v.u + 0x7FFFu + ((v.u >> 16) & 1u);  // RNE
  return (unsigned short)(r >> 16);
}
__device__ __forceinline__ float bf2f(unsigned short h) {
  union { unsigned u; float f; } v; v.u = ((unsigned)h) << 16;
  return v.f;
}

__device__ __forceinline__ void gload_lds16(const unsigned short* g, unsigned short* l) {
  __builtin_amdgcn_global_load_lds(
      (const __attribute__((address_space(1))) void*)g,
      (__attribute__((address_space(3))) void*)l,
      16, 0, 0);
}

__device__ __forceinline__ f32x4 mfma16(short8 a, short8 b, f32x4 c) {
  return __builtin_amdgcn_mfma_f32_16x16x32_bf16(a, b, c, 0, 0, 0);
}

// Stage a [128 rows][64 k] bf16 tile into linear LDS (16 KiB) via global_load_lds.
// XOR swizzle (chunk ^ (row&7)) applied on the GLOBAL source (rule #21).
__device__ __forceinline__ void stage_tile(const unsigned short* __restrict__ src,
                                           int row0, int k0,
                                           unsigned short* lds, int tid) {
#pragma unroll
  for (int i = 0; i < 4; ++i) {
    int s   = tid + 256 * i;      // 16B chunk slot, 1024 chunks total
    int row = s >> 3;             // 8 chunks (128B) per row
    int h   = s & 7;
    int gc  = h ^ (row & 7);      // inverse-swizzled source chunk
    const unsigned short* gp = src + (size_t)(row0 + row) * DIM + (size_t)(k0 + gc * 8);
    unsigned short* lp = lds + (size_t)((tid & ~63) + 256 * i) * 8;  // wave-uniform base
    gload_lds16(gp, lp);
  }
}

// Read one MFMA A/B fragment (contiguous k-permutation, ds_read_b128),
// applying the same XOR swizzle as the staging side.
__device__ __forceinline__ short8 read_frag(const unsigned short* lds, int rowbase,
                                            int r16, int g, int kk) {
  int row  = rowbase + r16;                 // rowbase multiple of 16 -> row&7 == r16&7
  int slot = (g + 4 * kk) ^ (r16 & 7);
  return *(const short8*)(lds + (size_t)row * 64 + (size_t)slot * 8);
}

// ---------------------------------------------------------------------------
__global__ void init_zero_k(float* __restrict__ out, float* __restrict__ norm2) {
  int i = blockIdx.x * 256 + threadIdx.x;
  if (i < ROWS) { out[i] = 0.f; norm2[i] = 0.f; }
}

__global__ void convert_x_k(const float4* __restrict__ x, ushort4* __restrict__ xb, int n4) {
  int i = blockIdx.x * 256 + threadIdx.x;
  if (i < n4) {
    float4 v = x[i];
    ushort4 o;
    o.x = f2bf(v.x); o.y = f2bf(v.y); o.z = f2bf(v.z); o.w = f2bf(v.w);
    xb[i] = o;
  }
}

// Wt[n][k] = W[k][n], bf16.  64x64 tiles via LDS.
__global__ void transpose_w_k(const float* __restrict__ W, unsigned short* __restrict__ Wt) {
  __shared__ unsigned short t[64][65];
  int bx = blockIdx.x & 15;   // col tile of W
  int by = blockIdx.x >> 4;   // row tile of W
  int c  = threadIdx.x & 63;
  int r0 = threadIdx.x >> 6;  // 0..3
#pragma unroll
  for (int i = 0; i < 16; ++i) {
    int r = r0 + i * 4;
    t[r][c] = f2bf(W[(size_t)(by * 64 + r) * DIM + (bx * 64 + c)]);
  }
  __syncthreads();
#pragma unroll
  for (int i = 0; i < 16; ++i) {
    int r = r0 + i * 4;  // row of Wt within tile = original col
    Wt[(size_t)(bx * 64 + r) * DIM + (by * 64 + c)] = t[c][r];
  }
}

// ---------------------------------------------------------------------------
// GEMM1: proj = Xb @ W  (B panel = rows of Wt). Writes bf16 proj + atomic sumsq.
__global__ __launch_bounds__(256) void gemm1_proj(
    const unsigned short* __restrict__ Xb,
    const unsigned short* __restrict__ Wt,
    unsigned short* __restrict__ projb,
    float* __restrict__ norm2) {
  __shared__ __align__(16) unsigned short lA[128 * 64];
  __shared__ __align__(16) unsigned short lB[128 * 64];
  const int tid = threadIdx.x;
  const int lane = tid & 63, wv = tid >> 6;
  const int wr = wv >> 1, wc = wv & 1;
  const int g = lane >> 4, r16 = lane & 15;
  const int mt = blockIdx.x >> 3, nt = blockIdx.x & 7;
  const int arow0 = mt * 128, brow0 = nt * 128;

  f32x4 acc[4][4];
#pragma unroll
  for (int m = 0; m < 4; ++m)
#pragma unroll
    for (int n = 0; n < 4; ++n) acc[m][n] = (f32x4){0.f, 0.f, 0.f, 0.f};

  for (int kt = 0; kt < DIM / 64; ++kt) {
    stage_tile(Xb, arow0, kt * 64, lA, tid);
    stage_tile(Wt, brow0, kt * 64, lB, tid);
    __syncthreads();
#pragma unroll
    for (int kk = 0; kk < 2; ++kk) {
      short8 af[4], bfr[4];
#pragma unroll
      for (int m = 0; m < 4; ++m) af[m] = read_frag(lA, wr * 64 + m * 16, r16, g, kk);
#pragma unroll
      for (int n = 0; n < 4; ++n) bfr[n] = read_frag(lB, wc * 64 + n * 16, r16, g, kk);
#pragma unroll
      for (int m = 0; m < 4; ++m)
#pragma unroll
        for (int n = 0; n < 4; ++n)
          acc[m][n] = mfma16(af[m], bfr[n], acc[m][n]);
    }
    __syncthreads();
  }

  // Epilogue: bf16 store + per-row sum-of-squares (reduce over lane&15 = cols).
#pragma unroll
  for (int m = 0; m < 4; ++m) {
#pragma unroll
    for (int r = 0; r < 4; ++r) {
      int row = arow0 + wr * 64 + m * 16 + 4 * g + r;
      float ss = 0.f;
#pragma unroll
      for (int n = 0; n < 4; ++n) {
        float v = acc[m][n][r];
        projb[(size_t)row * DIM + (brow0 + wc * 64 + n * 16 + r16)] = f2bf(v);
        ss += v * v;
      }
      ss += __shfl_xor(ss, 1);
      ss += __shfl_xor(ss, 2);
      ss += __shfl_xor(ss, 4);
      ss += __shfl_xor(ss, 8);
      if (r16 == 0) atomicAdd(&norm2[row], ss);
    }
  }
}

// ---------------------------------------------------------------------------
// GEMM2 (symmetric): only tiles st <= tt. Raw-dot MFMA on unnormalized projb;
// epilogue scales by rs_s*rs_t (rs = 1/max(||p||, eps)), applies sigmoid, and
// accumulates BOTH col-sums (-> out[t in C]) and, for off-diagonal tiles,
// row-sums (-> out[s in R], by symmetry sim[s,t]=sim[t,s]).
__global__ __launch_bounds__(256) void gemm2_attn(
    const unsigned short* __restrict__ projb,
    const float* __restrict__ norm2,
    float* __restrict__ out) {
  __shared__ __align__(16) unsigned short lA[128 * 64];
  __shared__ __align__(16) unsigned short lB[128 * 64];
  const int tid = threadIdx.x;
  const int lane = tid & 63, wv = tid >> 6;
  const int wr = wv >> 1, wc = wv & 1;
  const int g = lane >> 4, r16 = lane & 15;
  const int b = blockIdx.z;

  // Decode triangular pair index p -> (st, tt), st <= tt. Uniform scalar loop.
  int p = blockIdx.x;
  int st = 0, rem = p;
  while (rem >= (NT - st)) { rem -= (NT - st); ++st; }
  const int tt = st + rem;

  const unsigned short* Nb = projb + (size_t)b * SEQ * DIM;
  const float* n2b = norm2 + (size_t)b * SEQ;
  const int arow0 = st * 128, brow0 = tt * 128;
  const bool diag = (st == tt);

  f32x4 acc[4][4];
#pragma unroll
  for (int m = 0; m < 4; ++m)
#pragma unroll
    for (int n = 0; n < 4; ++n) acc[m][n] = (f32x4){0.f, 0.f, 0.f, 0.f};

  for (int kt = 0; kt < DIM / 64; ++kt) {
    stage_tile(Nb, arow0, kt * 64, lA, tid);
    if (!diag) stage_tile(Nb, brow0, kt * 64, lB, tid);
    __syncthreads();
    const unsigned short* lBr = diag ? lA : lB;
#pragma unroll
    for (int kk = 0; kk < 2; ++kk) {
      short8 af[4], bfr[4];
#pragma unroll
      for (int m = 0; m < 4; ++m) af[m] = read_frag(lA, wr * 64 + m * 16, r16, g, kk);
#pragma unroll
      for (int n = 0; n < 4; ++n) bfr[n] = read_frag(lBr, wc * 64 + n * 16, r16, g, kk);
#pragma unroll
      for (int m = 0; m < 4; ++m)
#pragma unroll
        for (int n = 0; n < 4; ++n)
          acc[m][n] = mfma16(af[m], bfr[n], acc[m][n]);
    }
    __syncthreads();
  }

  // Inverse norms for my rows (16) and cols (4).  rs = 1/max(sqrt(ss), eps).
  float rs_row[4][4], rs_col[4];
#pragma unroll
  for (int m = 0; m < 4; ++m)
#pragma unroll
    for (int r = 0; r < 4; ++r) {
      int row = arow0 + wr * 64 + m * 16 + 4 * g + r;
      rs_row[m][r] = 1.0f / fmaxf(sqrtf(n2b[row]), 1e-12f);
    }
#pragma unroll
  for (int n = 0; n < 4; ++n) {
    int col = brow0 + wc * 64 + n * 16 + r16;
    rs_col[n] = 1.0f / fmaxf(sqrtf(n2b[col]), 1e-12f);
  }

  const float inv = 1.0f / (float)SEQ;
  float rowacc[4][4];
#pragma unroll
  for (int m = 0; m < 4; ++m)
#pragma unroll
    for (int r = 0; r < 4; ++r) rowacc[m][r] = 0.f;

  // Sigmoid each element once; accumulate col partials (per n) + row partials.
#pragma unroll
  for (int n = 0; n < 4; ++n) {
    float colpart = 0.f;
#pragma unroll
    for (int m = 0; m < 4; ++m)
#pragma unroll
      for (int r = 0; r < 4; ++r) {
        float x = acc[m][n][r] * rs_row[m][r] * rs_col[n];
        float s = 1.0f / (1.0f + __expf(-x));
        colpart += s;
        rowacc[m][r] += s;
      }
    // reduce over rows held by other g-groups of this wave
    colpart += __shfl_xor(colpart, 16);
    colpart += __shfl_xor(colpart, 32);
    if (g == 0)
      atomicAdd(&out[(size_t)b * SEQ + brow0 + wc * 64 + n * 16 + r16], colpart * inv);
  }

  if (!diag) {
    // row sums over this wave's 64 cols -> out[s in R] (symmetry).
#pragma unroll
    for (int m = 0; m < 4; ++m)
#pragma unroll
      for (int r = 0; r < 4; ++r) {
        float rp = rowacc[m][r];
        rp += __shfl_xor(rp, 1);
        rp += __shfl_xor(rp, 2);
        rp += __shfl_xor(rp, 4);
        rp += __shfl_xor(rp, 8);
        if (r16 == 0)
          atomicAdd(&out[(size_t)b * SEQ + arow0 + wr * 64 + m * 16 + 4 * g + r], rp * inv);
      }
  }
}

// ---------------------------------------------------------------------------
extern "C" void kernel_launch(void* const* d_in, const int* in_sizes, int n_in,
                              void* d_out, int out_size, void* d_ws, size_t ws_size,
                              hipStream_t stream) {
  const float* x = (const float*)d_in[0];
  const float* W = (const float*)d_in[1];
  float* out = (float*)d_out;

  char* ws = (char*)d_ws;
  unsigned short* Xb    = (unsigned short*)ws;                                   // 64 MiB
  unsigned short* projb = (unsigned short*)(ws + (size_t)ROWS * DIM * 2);        // 64 MiB
  unsigned short* Wt    = (unsigned short*)(ws + (size_t)ROWS * DIM * 4);        // 2 MiB
  float* norm2          = (float*)(ws + (size_t)ROWS * DIM * 4 + (size_t)DIM * DIM * 2);

  hipLaunchKernelGGL(init_zero_k, dim3(ROWS / 256), dim3(256), 0, stream, out, norm2);
  hipLaunchKernelGGL(convert_x_k, dim3((ROWS * DIM / 4) / 256), dim3(256), 0, stream,
                     (const float4*)x, (ushort4*)Xb, ROWS * DIM / 4);
  hipLaunchKernelGGL(transpose_w_k, dim3(256), dim3(256), 0, stream, W, Wt);
  hipLaunchKernelGGL(gemm1_proj, dim3((ROWS / 128) * (DIM / 128)), dim3(256), 0, stream,
                     Xb, Wt, projb, norm2);
  hipLaunchKernelGGL(gemm2_attn, dim3(NPAIR, 1, BATCH), dim3(256), 0, stream,
                     projb, norm2, out);
}